// Round 11
// baseline (3152.945 us; speedup 1.0000x reference)
//
#include <hip/hip_runtime.h>
#include <hip/hip_bf16.h>
#include <stdint.h>

// Problem constants (B=8, S=2048, H=4096)
#define M_TOTAL 16384
#define K_DIM   4096
#define N_DIM   4096
#define BM 128
#define BN 128
#define BK 32
#define NK (K_DIM / BK)   // 128 K-steps
#define THREADS 512

typedef unsigned short u16;
typedef __attribute__((ext_vector_type(4))) float  f32x4;
typedef __attribute__((ext_vector_type(8))) short  bf16x8;   // 8 bf16 = 4 VGPRs (MFMA A/B frag)
typedef __attribute__((ext_vector_type(8))) unsigned short u16x8;

// ---- bf16 split helpers (round-to-nearest-even via bit trick) ----
__device__ __forceinline__ u16 f2bf_rn(float f) {
    union { float f; uint32_t u; } x; x.f = f;
    uint32_t r = x.u + 0x7FFFu + ((x.u >> 16) & 1u);
    return (u16)(r >> 16);
}
__device__ __forceinline__ float bf2f(u16 s) {
    union { uint32_t u; float f; } x; x.u = ((uint32_t)s) << 16;
    return x.f;
}

// ---- async global->LDS, 16B per lane ----
#define ASYNC16(gp, lp) \
    __builtin_amdgcn_global_load_lds((const __attribute__((address_space(1))) void*)(gp), \
                                     (__attribute__((address_space(3))) void*)(lp), 16, 0, 0)

// ============================================================
// Kernel 1: fp32 -> (bf16 hi, bf16 lo) split, 8 elems/thread
// ============================================================
__global__ __launch_bounds__(256) void split_kernel(const float* __restrict__ in,
                                                    u16* __restrict__ hi,
                                                    u16* __restrict__ lo,
                                                    int nvec) {   // nvec = n/8
    int i = blockIdx.x * 256 + threadIdx.x;
    if (i >= nvec) return;
    f32x4 v0 = ((const f32x4*)in)[2*i];
    f32x4 v1 = ((const f32x4*)in)[2*i + 1];
    u16x8 hv, lv;
#pragma unroll
    for (int j = 0; j < 8; ++j) {
        float f = (j < 4) ? v0[j] : v1[j - 4];
        u16 h = f2bf_rn(f);
        hv[j] = h;
        lv[j] = f2bf_rn(f - bf2f(h));
    }
    ((u16x8*)hi)[i] = hv;
    ((u16x8*)lo)[i] = lv;
}

// ============================================================
// Kernel 2: bf16x3 MFMA GEMM (NT) + bias + tanh-GELU
//   NEW vs R10 baseline:
//   - hi|lo merged k-wise into 128B LDS rows [row][64]: slot XOR-swizzle
//     (slot ^= row&7, 16B slots) kills the 8-way bank conflict (1.34e8 -> ~0).
//     Rule #21: linear gload_lds dest + inverse-swizzled per-lane SOURCE
//     (lane picks xh or xl) + swizzled read.
//   - triple-buffered counted-vmcnt pipeline (T4): 1 block x 512 thr/CU,
//     96KB LDS, 4 loads/thread/K-tile; loop waits vmcnt(4) (never 0),
//     stage t+2 issued right after barrier -> ~2 compute-phases of slack.
//   - B-hot XCD mapping kept (confirmed: FETCH 7.3GB -> 2.5GB).
// ============================================================
__global__ __launch_bounds__(THREADS, 1)
void gemm_gelu_kernel(const u16* __restrict__ xh, const u16* __restrict__ xl,
                      const u16* __restrict__ wh, const u16* __restrict__ wl,
                      const float* __restrict__ bias, float* __restrict__ out) {
    // [3 bufs][128 rows][64 bf16] each for A and B; row = 128B (8 x 16B slots)
    __shared__ __align__(16) u16 sA[3][BM * 64];
    __shared__ __align__(16) u16 sB[3][BN * 64];

    const int tid  = threadIdx.x;
    const int lane = tid & 63;
    const int wid  = tid >> 6;          // 8 waves

    // ---- B-hot XCD-aware mapping (bijective: 8 XCD x 2 rounds x 128 bm x 2 bn) ----
    const int bid = blockIdx.x;
    const int c  = bid & 7;          // XCD (round-robin dispatch)
    const int i  = bid >> 3;         // per-XCD sequence 0..511
    const int r  = i >> 8;           // round 0..1
    const int j  = i & 255;
    const int bm = j >> 1;           // 0..127
    const int bn = (c << 2) + (r << 1) + (j & 1);

    const int row0 = bm * BM;
    const int col0 = bn * BN;

    // ---- staging map: 4 instrs/thread. q0,q1 -> A slots 0..1023; q2,q3 -> B.
    // slot g: row = g>>3, phys slot sp = g&7; logical sl = sp ^ (row&7);
    // sl<4 -> hi array k-offset sl*8 ; sl>=4 -> lo array k-offset (sl&3)*8.
    const u16* src0; const u16* src1; const u16* src2; const u16* src3;
    int off0, off1, off2, off3;   // u16 index within one buffer
    {
        int g, row, sp, sl;
        g = tid;              row = g >> 3; sp = g & 7; sl = sp ^ (row & 7);
        src0 = ((sl < 4) ? xh : xl) + (size_t)(row0 + row) * K_DIM + (sl & 3) * 8;
        off0 = g * 8;
        g = 512 + tid;        row = g >> 3; sp = g & 7; sl = sp ^ (row & 7);
        src1 = ((sl < 4) ? xh : xl) + (size_t)(row0 + row) * K_DIM + (sl & 3) * 8;
        off1 = g * 8;
        g = tid;              row = g >> 3; sp = g & 7; sl = sp ^ (row & 7);   // B slots 0..511
        src2 = ((sl < 4) ? wh : wl) + (size_t)(col0 + row) * K_DIM + (sl & 3) * 8;
        off2 = g * 8;
        g = 512 + tid;        row = g >> 3; sp = g & 7; sl = sp ^ (row & 7);   // B slots 512..1023
        src3 = ((sl < 4) ? wh : wl) + (size_t)(col0 + row) * K_DIM + (sl & 3) * 8;
        off3 = g * 8;
    }

#define STAGE(buf, kt) { \
        const size_t kofs = (size_t)(kt) * BK; \
        ASYNC16(src0 + kofs, &sA[buf][off0]); \
        ASYNC16(src1 + kofs, &sA[buf][off1]); \
        ASYNC16(src2 + kofs, &sB[buf][off2]); \
        ASYNC16(src3 + kofs, &sB[buf][off3]); \
    }

    // wave tile: 32 rows x 64 cols  (wrow band 0..3, wcol band 0..1)
    const int wrow = (wid >> 1) << 5;
    const int wcol = (wid & 1) << 6;
    const int fr  = lane & 15;
    const int kq8 = lane >> 4;          // k-quad 0..3

    f32x4 acc[2][4] = {};

    // ---- prologue: stage K-tiles 0 and 1 ----
    STAGE(0, 0);
    STAGE(1, 1);

    for (int kt = 0; kt < NK - 1; ++kt) {
        const int cur = kt % 3;
        // wait: own stage(kt) complete (stage(kt+1)'s 4 loads still in flight)
        asm volatile("s_waitcnt vmcnt(4)" ::: "memory");
        __builtin_amdgcn_s_barrier();
        asm volatile("" ::: "memory");   // fence: nothing hoists above barrier

        if (kt + 2 < NK) STAGE((kt + 2) % 3, kt + 2);

        // ---- fragments (swizzled read) + 24 MFMA ----
        bf16x8 ah[2], al[2], bh[4], bl[4];
#pragma unroll
        for (int m = 0; m < 2; ++m) {
            const int rowA = wrow + m * 16 + fr;
            ah[m] = *(const bf16x8*)(sA[cur] + rowA * 64 + ((kq8      ) ^ (rowA & 7)) * 8);
            al[m] = *(const bf16x8*)(sA[cur] + rowA * 64 + ((kq8 | 4) ^ (rowA & 7)) * 8);
        }
#pragma unroll
        for (int n = 0; n < 4; ++n) {
            const int rowB = wcol + n * 16 + fr;
            bh[n] = *(const bf16x8*)(sB[cur] + rowB * 64 + ((kq8      ) ^ (rowB & 7)) * 8);
            bl[n] = *(const bf16x8*)(sB[cur] + rowB * 64 + ((kq8 | 4) ^ (rowB & 7)) * 8);
        }
#pragma unroll
        for (int m = 0; m < 2; ++m)
#pragma unroll
            for (int n = 0; n < 4; ++n) {
                acc[m][n] = __builtin_amdgcn_mfma_f32_16x16x32_bf16(al[m], bh[n], acc[m][n], 0, 0, 0);
                acc[m][n] = __builtin_amdgcn_mfma_f32_16x16x32_bf16(ah[m], bl[n], acc[m][n], 0, 0, 0);
                acc[m][n] = __builtin_amdgcn_mfma_f32_16x16x32_bf16(ah[m], bh[n], acc[m][n], 0, 0, 0);
            }
    }

    // ---- peeled last iteration: full drain ----
    {
        const int cur = (NK - 1) % 3;
        asm volatile("s_waitcnt vmcnt(0)" ::: "memory");
        __builtin_amdgcn_s_barrier();
        asm volatile("" ::: "memory");
        bf16x8 ah[2], al[2], bh[4], bl[4];
#pragma unroll
        for (int m = 0; m < 2; ++m) {
            const int rowA = wrow + m * 16 + fr;
            ah[m] = *(const bf16x8*)(sA[cur] + rowA * 64 + ((kq8      ) ^ (rowA & 7)) * 8);
            al[m] = *(const bf16x8*)(sA[cur] + rowA * 64 + ((kq8 | 4) ^ (rowA & 7)) * 8);
        }
#pragma unroll
        for (int n = 0; n < 4; ++n) {
            const int rowB = wcol + n * 16 + fr;
            bh[n] = *(const bf16x8*)(sB[cur] + rowB * 64 + ((kq8      ) ^ (rowB & 7)) * 8);
            bl[n] = *(const bf16x8*)(sB[cur] + rowB * 64 + ((kq8 | 4) ^ (rowB & 7)) * 8);
        }
#pragma unroll
        for (int m = 0; m < 2; ++m)
#pragma unroll
            for (int n = 0; n < 4; ++n) {
                acc[m][n] = __builtin_amdgcn_mfma_f32_16x16x32_bf16(al[m], bh[n], acc[m][n], 0, 0, 0);
                acc[m][n] = __builtin_amdgcn_mfma_f32_16x16x32_bf16(ah[m], bl[n], acc[m][n], 0, 0, 0);
                acc[m][n] = __builtin_amdgcn_mfma_f32_16x16x32_bf16(ah[m], bh[n], acc[m][n], 0, 0, 0);
            }
    }
#undef STAGE

    // ---- epilogue: bias + tanh-GELU, write g to out (fp32) ----
    // C/D layout (verified m89/m91): col = lane&15, row = (lane>>4)*4 + reg
    const float SC = 0.7978845608028654f;  // sqrt(2/pi)
#pragma unroll
    for (int n = 0; n < 4; ++n) {
        const int col = col0 + wcol + n * 16 + (lane & 15);
        const float bc = bias[col];
#pragma unroll
        for (int m = 0; m < 2; ++m) {
            const int rbase = row0 + wrow + m * 16 + ((lane >> 4) << 2);
#pragma unroll
            for (int rr = 0; rr < 4; ++rr) {
                float h = acc[m][n][rr] + bc;
                float t = tanhf(SC * (h + 0.044715f * h * h * h));
                out[(size_t)(rbase + rr) * N_DIM + col] = 0.5f * h * (1.0f + t);
            }
        }
    }
}

// ============================================================
// Kernel 3: in-place row LayerNorm (biased var, eps=1e-12), two-pass
// ============================================================
__global__ __launch_bounds__(256)
void ln_kernel(float* __restrict__ out, const float* __restrict__ a2,
               const float* __restrict__ b2) {
    const int row = blockIdx.x;
    float* g = out + (size_t)row * N_DIM;
    const int tid = threadIdx.x;

    f32x4 v[4];
    float s = 0.f;
#pragma unroll
    for (int j = 0; j < 4; ++j) {
        v[j] = ((const f32x4*)g)[j * 256 + tid];
        s += v[j][0] + v[j][1] + v[j][2] + v[j][3];
    }
#pragma unroll
    for (int o = 32; o > 0; o >>= 1) s += __shfl_xor(s, o, 64);
    __shared__ float red[4];
    if ((tid & 63) == 0) red[tid >> 6] = s;
    __syncthreads();
    s = red[0] + red[1] + red[2] + red[3];
    const float mean = s * (1.0f / N_DIM);

    float q = 0.f;
#pragma unroll
    for (int j = 0; j < 4; ++j)
#pragma unroll
        for (int e = 0; e < 4; ++e) { float d = v[j][e] - mean; q += d * d; }
#pragma unroll
    for (int o = 32; o > 0; o >>= 1) q += __shfl_xor(q, o, 64);
    __shared__ float red2[4];
    if ((tid & 63) == 0) red2[tid >> 6] = q;
    __syncthreads();
    q = red2[0] + red2[1] + red2[2] + red2[3];
    const float var = q * (1.0f / N_DIM);
    const float inv = 1.0f / sqrtf(var + 1e-12f);

#pragma unroll
    for (int j = 0; j < 4; ++j) {
        f32x4 av = ((const f32x4*)a2)[j * 256 + tid];
        f32x4 bv = ((const f32x4*)b2)[j * 256 + tid];
        f32x4 o4;
#pragma unroll
        for (int e = 0; e < 4; ++e) o4[e] = (v[j][e] - mean) * inv * av[e] + bv[e];
        ((f32x4*)g)[j * 256 + tid] = o4;
    }
}

// ============================================================
extern "C" void kernel_launch(void* const* d_in, const int* in_sizes, int n_in,
                              void* d_out, int out_size, void* d_ws, size_t ws_size,
                              hipStream_t stream) {
    const float* x  = (const float*)d_in[0];   // [16384, 4096]
    const float* W  = (const float*)d_in[1];   // [4096, 4096] (torch [out,in])
    const float* b  = (const float*)d_in[2];
    const float* a2 = (const float*)d_in[3];
    const float* b2 = (const float*)d_in[4];
    float* out = (float*)d_out;

    // workspace layout (320 MiB total): xh 128MiB | xl 128MiB | wh 32MiB | wl 32MiB
    char* ws = (char*)d_ws;
    u16* xh = (u16*)(ws);
    u16* xl = (u16*)(ws + 134217728ull);
    u16* wh = (u16*)(ws + 268435456ull);
    u16* wl = (u16*)(ws + 301989888ull);

    split_kernel<<<8388608 / 256, 256, 0, stream>>>(x, xh, xl, 8388608);
    split_kernel<<<2097152 / 256, 256, 0, stream>>>(W, wh, wl, 2097152);

    // GEMM + bias + GELU: grid = 128 bm * 32 bn = 4096, 512 threads
    gemm_gelu_kernel<<<4096, THREADS, 0, stream>>>(xh, xl, wh, wl, b, out);

    // LayerNorm in-place: one block per row
    ln_kernel<<<M_TOTAL, 256, 0, stream>>>(out, a2, b2);
}

// Round 14
// 2223.180 us; speedup vs baseline: 1.4182x; 1.4182x over previous
//
#include <hip/hip_runtime.h>
#include <hip/hip_bf16.h>
#include <stdint.h>

// Problem constants (B=8, S=2048, H=4096)
#define M_TOTAL 16384
#define K_DIM   4096
#define N_DIM   4096
#define BM 128
#define BN 128
#define BK 32
#define NK (K_DIM / BK)   // 128 K-steps

typedef unsigned short u16;
typedef __attribute__((ext_vector_type(4))) float  f32x4;
typedef __attribute__((ext_vector_type(8))) short  bf16x8;   // 8 bf16 = 4 VGPRs (MFMA A/B frag)
typedef __attribute__((ext_vector_type(8))) unsigned short u16x8;

// ---- bf16 split helpers (round-to-nearest-even via bit trick) ----
__device__ __forceinline__ u16 f2bf_rn(float f) {
    union { float f; uint32_t u; } x; x.f = f;
    uint32_t r = x.u + 0x7FFFu + ((x.u >> 16) & 1u);
    return (u16)(r >> 16);
}
__device__ __forceinline__ float bf2f(u16 s) {
    union { uint32_t u; float f; } x; x.u = ((uint32_t)s) << 16;
    return x.f;
}

// ---- async global->LDS, 16B per lane ----
#define ASYNC16(gp, lp) \
    __builtin_amdgcn_global_load_lds((const __attribute__((address_space(1))) void*)(gp), \
                                     (__attribute__((address_space(3))) void*)(lp), 16, 0, 0)

// ============================================================
// Kernel 1: fp32 -> (bf16 hi, bf16 lo) split, 8 elems/thread
// ============================================================
__global__ __launch_bounds__(256) void split_kernel(const float* __restrict__ in,
                                                    u16* __restrict__ hi,
                                                    u16* __restrict__ lo,
                                                    int nvec) {   // nvec = n/8
    int i = blockIdx.x * 256 + threadIdx.x;
    if (i >= nvec) return;
    f32x4 v0 = ((const f32x4*)in)[2*i];
    f32x4 v1 = ((const f32x4*)in)[2*i + 1];
    u16x8 hv, lv;
#pragma unroll
    for (int j = 0; j < 8; ++j) {
        float f = (j < 4) ? v0[j] : v1[j - 4];
        u16 h = f2bf_rn(f);
        hv[j] = h;
        lv[j] = f2bf_rn(f - bf2f(h));
    }
    ((u16x8*)hi)[i] = hv;
    ((u16x8*)lo)[i] = lv;
}

// ============================================================
// Kernel 2: bf16x3 MFMA GEMM (NT) + bias + tanh-GELU
//   Composition of proven pieces only (R10/R11 post-mortems):
//   - R10 structure: 256 thr / 4 waves / 64x64 wave tile / 2 blocks/CU
//   - R11 LDS layout: merged hi|lo 128B rows + 16B-slot XOR swizzle
//     (SQ_LDS_BANK_CONFLICT 1.34e8 -> 0, verified)
//   - T4 counted vmcnt: STAGE(t+1) in flight ACROSS both barriers;
//     vmcnt(8) waits only for stage(t); never drains to 0 in-loop
//   - B-hot XCD mapping (FETCH 7.3GB -> 2.4GB, verified)
// ============================================================
__global__ __launch_bounds__(256, 2)
void gemm_gelu_kernel(const u16* __restrict__ xh, const u16* __restrict__ xl,
                      const u16* __restrict__ wh, const u16* __restrict__ wl,
                      const float* __restrict__ bias, float* __restrict__ out) {
    // [2 bufs][128 rows][64 bf16] each for A and B; row = 128B = 8 x 16B slots
    __shared__ __align__(16) u16 sA[2][BM * 64];
    __shared__ __align__(16) u16 sB[2][BN * 64];

    const int tid  = threadIdx.x;
    const int lane = tid & 63;
    const int wid  = tid >> 6;          // 4 waves

    // ---- B-hot XCD-aware mapping (bijective: 8 XCD x 2 rounds x 128 bm x 2 bn) ----
    const int bid = blockIdx.x;
    const int c  = bid & 7;          // XCD (round-robin dispatch)
    const int i  = bid >> 3;         // per-XCD sequence 0..511
    const int r  = i >> 8;           // round 0..1
    const int j  = i & 255;
    const int bm = j >> 1;           // 0..127
    const int bn = (c << 2) + (r << 1) + (j & 1);

    const int row0 = bm * BM;
    const int col0 = bn * BN;

    // ---- staging map: 8 loads/thread (4 A-slots + 4 B-slots of 1024 each).
    // slot g: row = g>>3, phys slot sp = g&7, logical sl = sp ^ (row&7);
    // sl<4 -> hi array, k-offset sl*8 ; sl>=4 -> lo array, k-offset (sl&3)*8.
    // (linear gload_lds dest; swizzle applied via per-lane SOURCE address)
    const u16* srcA[4]; const u16* srcB[4]; int offAB[4];
#pragma unroll
    for (int q = 0; q < 4; ++q) {
        const int g = q * 256 + tid, row = g >> 3, sp = g & 7, sl = sp ^ (row & 7);
        srcA[q] = ((sl < 4) ? xh : xl) + (size_t)(row0 + row) * K_DIM + (sl & 3) * 8;
        srcB[q] = ((sl < 4) ? wh : wl) + (size_t)(col0 + row) * K_DIM + (sl & 3) * 8;
        offAB[q] = g * 8;
    }

#define STAGE(buf, kt) { \
        const size_t kofs = (size_t)(kt) * BK; \
        _Pragma("unroll") \
        for (int q = 0; q < 4; ++q) { \
            ASYNC16(srcA[q] + kofs, &sA[buf][offAB[q]]); \
            ASYNC16(srcB[q] + kofs, &sB[buf][offAB[q]]); \
        } \
    }

    // wave tile: 64 rows x 64 cols
    const int wrow = (wid >> 1) << 6;
    const int wcol = (wid & 1) << 6;
    const int fr  = lane & 15;
    const int kq8 = lane >> 4;          // k-quad 0..3

    f32x4 acc[4][4] = {};

    // ---- prologue: stage K-tile 0 ----
    STAGE(0, 0);

    for (int kt = 0; kt < NK; ++kt) {
        const int cur = kt & 1;
        if (kt + 1 < NK) {
            STAGE(cur ^ 1, kt + 1);   // 8 loads; stay in flight across barriers
            asm volatile("s_waitcnt vmcnt(8)" ::: "memory");  // stage(kt) landed
        } else {
            asm volatile("s_waitcnt vmcnt(0)" ::: "memory");  // final drain
        }
        __builtin_amdgcn_s_barrier();      // A: all waves' stage(kt) complete
        asm volatile("" ::: "memory");

        // ---- fragments (swizzled read, conflict-free) + 48 MFMA ----
        bf16x8 bh[4], bl[4];
#pragma unroll
        for (int n = 0; n < 4; ++n) {
            const int rowB = wcol + n * 16 + fr;
            const u16* base = sB[cur] + rowB * 64;
            bh[n] = *(const bf16x8*)(base + ((kq8      ) ^ (rowB & 7)) * 8);
            bl[n] = *(const bf16x8*)(base + ((kq8 | 4) ^ (rowB & 7)) * 8);
        }
#pragma unroll
        for (int m = 0; m < 4; ++m) {
            const int rowA = wrow + m * 16 + fr;
            const u16* baseA = sA[cur] + rowA * 64;
            bf16x8 ah = *(const bf16x8*)(baseA + ((kq8      ) ^ (rowA & 7)) * 8);
            bf16x8 al = *(const bf16x8*)(baseA + ((kq8 | 4) ^ (rowA & 7)) * 8);
#pragma unroll
            for (int n = 0; n < 4; ++n) {
                // small terms first (fp32 accumulation order), big term last
                acc[m][n] = __builtin_amdgcn_mfma_f32_16x16x32_bf16(al, bh[n], acc[m][n], 0, 0, 0);
                acc[m][n] = __builtin_amdgcn_mfma_f32_16x16x32_bf16(ah, bl[n], acc[m][n], 0, 0, 0);
                acc[m][n] = __builtin_amdgcn_mfma_f32_16x16x32_bf16(ah, bh[n], acc[m][n], 0, 0, 0);
            }
        }

        asm volatile("" ::: "memory");
        __builtin_amdgcn_s_barrier();      // B: all reads of buf[cur] retired
        // -> next epoch may overwrite buf[cur]; stage(kt+1) still in flight
    }
#undef STAGE

    // ---- epilogue: bias + tanh-GELU, write g to out (fp32) ----
    // C/D layout (verified m89/m91): col = lane&15, row = (lane>>4)*4 + reg
    const float SC = 0.7978845608028654f;  // sqrt(2/pi)
#pragma unroll
    for (int n = 0; n < 4; ++n) {
        const int col = col0 + wcol + n * 16 + (lane & 15);
        const float bc = bias[col];
#pragma unroll
        for (int m = 0; m < 4; ++m) {
            const int rbase = row0 + wrow + m * 16 + ((lane >> 4) << 2);
#pragma unroll
            for (int rr = 0; rr < 4; ++rr) {
                float h = acc[m][n][rr] + bc;
                float t = tanhf(SC * (h + 0.044715f * h * h * h));
                out[(size_t)(rbase + rr) * N_DIM + col] = 0.5f * h * (1.0f + t);
            }
        }
    }
}

// ============================================================
// Kernel 3: in-place row LayerNorm (biased var, eps=1e-12), two-pass
// ============================================================
__global__ __launch_bounds__(256)
void ln_kernel(float* __restrict__ out, const float* __restrict__ a2,
               const float* __restrict__ b2) {
    const int row = blockIdx.x;
    float* g = out + (size_t)row * N_DIM;
    const int tid = threadIdx.x;

    f32x4 v[4];
    float s = 0.f;
#pragma unroll
    for (int j = 0; j < 4; ++j) {
        v[j] = ((const f32x4*)g)[j * 256 + tid];
        s += v[j][0] + v[j][1] + v[j][2] + v[j][3];
    }
#pragma unroll
    for (int o = 32; o > 0; o >>= 1) s += __shfl_xor(s, o, 64);
    __shared__ float red[4];
    if ((tid & 63) == 0) red[tid >> 6] = s;
    __syncthreads();
    s = red[0] + red[1] + red[2] + red[3];
    const float mean = s * (1.0f / N_DIM);

    float q = 0.f;
#pragma unroll
    for (int j = 0; j < 4; ++j)
#pragma unroll
        for (int e = 0; e < 4; ++e) { float d = v[j][e] - mean; q += d * d; }
#pragma unroll
    for (int o = 32; o > 0; o >>= 1) q += __shfl_xor(q, o, 64);
    __shared__ float red2[4];
    if ((tid & 63) == 0) red2[tid >> 6] = q;
    __syncthreads();
    q = red2[0] + red2[1] + red2[2] + red2[3];
    const float var = q * (1.0f / N_DIM);
    const float inv = 1.0f / sqrtf(var + 1e-12f);

#pragma unroll
    for (int j = 0; j < 4; ++j) {
        f32x4 av = ((const f32x4*)a2)[j * 256 + tid];
        f32x4 bv = ((const f32x4*)b2)[j * 256 + tid];
        f32x4 o4;
#pragma unroll
        for (int e = 0; e < 4; ++e) o4[e] = (v[j][e] - mean) * inv * av[e] + bv[e];
        ((f32x4*)g)[j * 256 + tid] = o4;
    }
}

// ============================================================
extern "C" void kernel_launch(void* const* d_in, const int* in_sizes, int n_in,
                              void* d_out, int out_size, void* d_ws, size_t ws_size,
                              hipStream_t stream) {
    const float* x  = (const float*)d_in[0];   // [16384, 4096]
    const float* W  = (const float*)d_in[1];   // [4096, 4096] (torch [out,in])
    const float* b  = (const float*)d_in[2];
    const float* a2 = (const float*)d_in[3];
    const float* b2 = (const float*)d_in[4];
    float* out = (float*)d_out;

    // workspace layout (320 MiB total): xh 128MiB | xl 128MiB | wh 32MiB | wl 32MiB
    char* ws = (char*)d_ws;
    u16* xh = (u16*)(ws);
    u16* xl = (u16*)(ws + 134217728ull);
    u16* wh = (u16*)(ws + 268435456ull);
    u16* wl = (u16*)(ws + 301989888ull);

    split_kernel<<<8388608 / 256, 256, 0, stream>>>(x, xh, xl, 8388608);
    split_kernel<<<2097152 / 256, 256, 0, stream>>>(W, wh, wl, 2097152);

    // GEMM + bias + GELU: grid = 128 bm * 32 bn = 4096
    gemm_gelu_kernel<<<4096, 256, 0, stream>>>(xh, xl, wh, wl, b, out);

    // LayerNorm in-place: one block per row
    ln_kernel<<<M_TOTAL, 256, 0, stream>>>(out, a2, b2);
}